// Round 5
// baseline (254.173 us; speedup 1.0000x reference)
//
#include <hip/hip_runtime.h>

// ===== R5: DIAGNOSTIC ROUND =====
// Identical algorithm to R4 (passed, 89.9us, absmax 0) but the whole
// computation runs REPEAT=3 times inside one dispatch. Each repeat reloads
// the (unchanged) input and rewrites identical output values, so the result
// is bit-identical and deterministic. Purpose: dispatch duration ~270us >
// the harness's 245us fillBuffer dispatches, so OUR kernel surfaces in the
// rocprof top-5 and we finally get VALUBusy / Occupancy / FETCH / WRITE /
// hbm_gbps for the stencil itself (3 rounds of structural changes were all
// 90.5 +/- 0.8us; need counters to pick the next lever).
//
// Algorithm (R4): halo/trapezoid decomposition. Block owns T=32 rows of n
// for one (b, d-half); loads R=144 rows (56 halo each side, wraparound);
// runs all 50 steps in registers (K=9 f4/thread); per-step boundary
// exchange via double-buffered LDS board + raw s_barrier (lgkmcnt only);
// nontemporal coalesced stores of owned rows each step.

namespace {

typedef float f4 __attribute__((ext_vector_type(4)));

constexpr int   REPEAT = 3;     // diagnostic replication (R5 only)
constexpr int   B      = 8;
constexpr int   N      = 2048;
constexpr int   D4     = 32;    // 128 floats = 32 float4 per row (global)
constexpr int   SPLITD = 2;     // d-halves per row
constexpr int   D4L    = D4 / SPLITD;  // 16 float4 lanes per block
constexpr int   STEPS  = 50;
constexpr float ALPHA  = 0.1f;
constexpr int   T      = 32;    // owned rows per block
constexpr int   QG     = 16;    // row-groups per block (256 thr / 16 lanes)
constexpr int   K      = 9;     // rows per thread
constexpr int   R      = QG * K;        // 144 staged rows
constexpr int   HALO_L = (R - T) / 2;   // 56 >= 50 needed
constexpr int   CHUNKS = N / T; // 64 chunks per batch

__device__ __forceinline__ f4 stencil(const f4 p, const f4 c, const f4 n) {
    return c + ALPHA * (p + n - 2.0f * c);
}

__global__ __launch_bounds__(QG * D4L, 4) void diffusion_halo(
        const f4* __restrict__ in4, f4* __restrict__ out4) {
    const int tid = threadIdx.x;
    const int d4l = tid & (D4L - 1);  // float4 lane within this d-half
    const int q   = tid >> 4;         // row-group 0..15

    const int bid = blockIdx.x;
    const int dh  = bid & (SPLITD - 1);            // d-half
    const int c   = (bid >> 1) & (CHUNKS - 1);     // n-chunk
    const int b   = bid >> 7;                      // batch (1024/128)
    const int n0  = c * T;
    const int d4g = dh * D4L + d4l;                // global float4 column

    // Double-buffered boundary board: one barrier per step.
    __shared__ f4 lo[2][QG][D4L];
    __shared__ f4 hi[2][QG][D4L];

    const int rbase = q * K;

    for (int rep = 0; rep < REPEAT; ++rep) {
        f4 s[K];
        // Load R rows with wraparound: ng = (n0 + r - HALO_L) mod N.
#pragma unroll
        for (int i = 0; i < K; ++i) {
            const int ng = (n0 + rbase + i + (N - HALO_L)) & (N - 1);
            s[i] = in4[(b * N + ng) * D4 + d4g];
        }

        // out[0] = initial state (owned rows only)
#pragma unroll
        for (int i = 0; i < K; ++i) {
            const int r = rbase + i;
            if (r >= HALO_L && r < HALO_L + T) {
                __builtin_nontemporal_store(
                    s[i], &out4[(b * N + (n0 + r - HALO_L)) * D4 + d4g]);
            }
        }

        for (int k = 1; k <= STEPS; ++k) {
            const int buf = k & 1;
            // Publish old boundary rows of this group.
            lo[buf][q][d4l] = s[0];
            hi[buf][q][d4l] = s[K - 1];
            // LDS ordering only — stores stay in flight across barrier.
            asm volatile("s_waitcnt lgkmcnt(0)" ::: "memory");
            __builtin_amdgcn_s_barrier();
            const f4 bl = (q > 0)      ? hi[buf][q - 1][d4l] : (f4)(0.f);
            const f4 bh = (q < QG - 1) ? lo[buf][q + 1][d4l] : (f4)(0.f);
            // No second barrier: next iter writes buf^1; reuse of buf two
            // steps later is fenced by intervening lgkmcnt(0)+barrier.

            // In-register carry-chain stencil; store owned rows as made.
            const int outbase = (k * B + b) * N;
            f4 prev = bl;
#pragma unroll
            for (int i = 0; i < K; ++i) {
                const f4 cur = s[i];
                f4 nxt = bh;
                if (i + 1 < K) nxt = s[i + 1];
                s[i] = stencil(prev, cur, nxt);
                prev = cur;
                const int r = rbase + i;
                if (r >= HALO_L && r < HALO_L + T) {
                    __builtin_nontemporal_store(
                        s[i],
                        &out4[(outbase + (n0 + r - HALO_L)) * D4 + d4g]);
                }
            }
        }
        // Repeat-boundary safety: last reads of buf happened >=1 barrier
        // ago for buf=0 (k=50); next repeat first writes buf=1. Same
        // steady-state argument as in-loop; no extra fence needed.
    }
}

}  // namespace

extern "C" void kernel_launch(void* const* d_in, const int* in_sizes, int n_in,
                              void* d_out, int out_size, void* d_ws, size_t ws_size,
                              hipStream_t stream) {
    const f4* in4  = reinterpret_cast<const f4*>(d_in[0]);
    f4*       out4 = reinterpret_cast<f4*>(d_out);

    dim3 grid(B * CHUNKS * SPLITD);  // 1024 blocks -> 4 per CU
    dim3 block(QG * D4L);            // 256 threads
    diffusion_halo<<<grid, block, 0, stream>>>(in4, out4);
}